// Round 2
// baseline (2126.948 us; speedup 1.0000x reference)
//
#include <hip/hip_runtime.h>
#include <hip/hip_bf16.h>
#include <cstddef>

#define H_    256
#define INP_  128
#define A_    64
#define F_    1024
#define V_    50000
#define S_    512
#define T_    32
#define B_    32
#define G4_   1024   // 4*H

typedef __attribute__((ext_vector_type(8))) short bf16x8;
typedef __attribute__((ext_vector_type(4))) float f32x4;

__device__ __forceinline__ float sigm_f(float x) { return 1.f / (1.f + __expf(-x)); }
__device__ __forceinline__ float tanh_f(float x) { float e = __expf(2.f * x); return 1.f - 2.f / (e + 1.f); }

__device__ __forceinline__ unsigned short bf16_rne(float f) {
    unsigned u = __float_as_uint(f);
    u += 0x7FFFu + ((u >> 16) & 1u);
    return (unsigned short)(u >> 16);
}

__device__ __forceinline__ float wred_max(float v) {
#pragma unroll
    for (int o = 1; o < 64; o <<= 1) v = fmaxf(v, __shfl_xor(v, o));
    return v;
}
__device__ __forceinline__ float wred_sum(float v) {
#pragma unroll
    for (int o = 1; o < 64; o <<= 1) v += __shfl_xor(v, o);
    return v;
}

// ---------------- transpose W_hh (1024x256) -> WT (256x1024), both layers ----------------
__global__ __launch_bounds__(256) void k_transpose_whh(const float* __restrict__ W0,
                                                       const float* __restrict__ W1,
                                                       float* __restrict__ T0,
                                                       float* __restrict__ T1) {
    int idx = blockIdx.x * 256 + threadIdx.x;
    int layer = idx >> 18;
    int i = idx & 262143;
    int k = i >> 10;
    int r = i & 1023;
    const float* W = layer ? W1 : W0;
    float* Tp = layer ? T1 : T0;
    Tp[i] = W[r * H_ + k];
}

// ---------------- reduce: new_enc/new_cell (2,B,H) ----------------
__global__ __launch_bounds__(256) void k_reduce(const float* __restrict__ hid,
                                                const float* __restrict__ cel,
                                                const float* __restrict__ Wred,
                                                const float* __restrict__ bred,
                                                float* __restrict__ ne,
                                                float* __restrict__ nc) {
    int idx = blockIdx.x * 256 + threadIdx.x;
    int arr = idx >> 14;
    int rem = idx & 16383;
    int l = rem >> 13;
    int b = (rem >> 8) & 31;
    int j = rem & 255;
    const float* src = arr ? cel : hid;
    const float* w = Wred + j * 512;
    const float* s0 = src + (l * B_ + b) * H_;
    const float* s1 = src + ((l + 2) * B_ + b) * H_;
    float acc = bred[j];
#pragma unroll 8
    for (int d = 0; d < 256; ++d) acc += s0[d] * w[d];
#pragma unroll 8
    for (int d = 0; d < 256; ++d) acc += s1[d] * w[256 + d];
    float* dst = arr ? nc : ne;
    dst[l * (B_ * H_) + b * H_ + j] = acc;
}

// ---------------- generic 64x64 f32 GEMM (NT): C[m,n] = sum_k A[m,k]*B[n,k] + bias ----------------
__global__ __launch_bounds__(256) void k_gemm64(const float* __restrict__ A, int lda,
                                                const float* __restrict__ Bm, int ldb,
                                                const float* __restrict__ bias1,
                                                const float* __restrict__ bias2,
                                                float* __restrict__ C, int ldc, int K) {
    __shared__ float As[32 * 65];
    __shared__ float Bs[32 * 65];
    int tid = threadIdx.x;
    int m0 = blockIdx.x * 64, n0 = blockIdx.y * 64;
    int mym = (tid >> 4) * 4, myn = (tid & 15) * 4;
    float c[4][4] = {};
    for (int k0 = 0; k0 < K; k0 += 32) {
        __syncthreads();
#pragma unroll
        for (int p = 0; p < 8; ++p) {
            int idx = tid + p * 256;
            int k = idx & 31, m = idx >> 5;
            As[k * 65 + m] = A[(size_t)(m0 + m) * lda + k0 + k];
            Bs[k * 65 + m] = Bm[(size_t)(n0 + m) * ldb + k0 + k];
        }
        __syncthreads();
#pragma unroll
        for (int k = 0; k < 32; ++k) {
            float a0 = As[k * 65 + mym + 0];
            float a1 = As[k * 65 + mym + 1];
            float a2 = As[k * 65 + mym + 2];
            float a3 = As[k * 65 + mym + 3];
            float b0 = Bs[k * 65 + myn + 0];
            float b1 = Bs[k * 65 + myn + 1];
            float b2 = Bs[k * 65 + myn + 2];
            float b3 = Bs[k * 65 + myn + 3];
            c[0][0] += a0 * b0; c[0][1] += a0 * b1; c[0][2] += a0 * b2; c[0][3] += a0 * b3;
            c[1][0] += a1 * b0; c[1][1] += a1 * b1; c[1][2] += a1 * b2; c[1][3] += a1 * b3;
            c[2][0] += a2 * b0; c[2][1] += a2 * b1; c[2][2] += a2 * b2; c[2][3] += a2 * b3;
            c[3][0] += a3 * b0; c[3][1] += a3 * b1; c[3][2] += a3 * b2; c[3][3] += a3 * b3;
        }
    }
    float bj[4];
#pragma unroll
    for (int j = 0; j < 4; ++j) {
        int n = n0 + myn + j;
        bj[j] = (bias1 ? bias1[n] : 0.f) + (bias2 ? bias2[n] : 0.f);
    }
#pragma unroll
    for (int i = 0; i < 4; ++i) {
        size_t off = (size_t)(m0 + mym + i) * ldc + n0 + myn;
#pragma unroll
        for (int j = 0; j < 4; ++j) C[off + j] = c[i][j] + bj[j];
    }
}

// ---------------- LSTM layer: one block per batch element, recurrence in LDS ----------------
__global__ __launch_bounds__(1024) void k_lstm(const float* __restrict__ gx,
                                               const float* __restrict__ WT,   // (256,1024) k-major
                                               const float* __restrict__ h0,
                                               const float* __restrict__ c0,
                                               float* __restrict__ y, int ldy,
                                               float* __restrict__ outh,
                                               float* __restrict__ outc) {
    int b = blockIdx.x, tid = threadIdx.x;
    __shared__ float h_s[256], c_s[256], g_s[1024];
    if (tid < 256) { h_s[tid] = h0[b * H_ + tid]; c_s[tid] = c0[b * H_ + tid]; }
    __syncthreads();
    for (int t = 0; t < T_; ++t) {
        float base = gx[(size_t)(t * B_ + b) * G4_ + tid];
        const float* wp = WT + tid;
        float a0 = 0.f, a1 = 0.f, a2 = 0.f, a3 = 0.f;
#pragma unroll 2
        for (int k = 0; k < 256; k += 4) {
            a0 += wp[(size_t)(k + 0) * G4_] * h_s[k + 0];
            a1 += wp[(size_t)(k + 1) * G4_] * h_s[k + 1];
            a2 += wp[(size_t)(k + 2) * G4_] * h_s[k + 2];
            a3 += wp[(size_t)(k + 3) * G4_] * h_s[k + 3];
        }
        g_s[tid] = base + (a0 + a1) + (a2 + a3);
        __syncthreads();
        if (tid < 256) {
            float ii = sigm_f(g_s[tid]);
            float ff = sigm_f(g_s[256 + tid]);
            float gg = tanh_f(g_s[512 + tid]);
            float oo = sigm_f(g_s[768 + tid]);
            float cc = ff * c_s[tid] + ii * gg;
            float hh = oo * tanh_f(cc);
            c_s[tid] = cc; h_s[tid] = hh;
            y[(size_t)(t * B_ + b) * ldy + tid] = hh;
        }
        __syncthreads();
    }
    if (tid < 256) { outh[b * H_ + tid] = h_s[tid]; outc[b * H_ + tid] = c_s[tid]; }
}

// ---------------- attention scan: sequential part only (no enc reads) ----------------
__global__ __launch_bounds__(512) void k_att_scan(const float* __restrict__ encp,     // (S*B,64)
                                                  const float* __restrict__ decp,     // (T*B,64)
                                                  const float* __restrict__ Watt,     // (64,769)
                                                  const float* __restrict__ Wout,     // (64,)
                                                  const float* __restrict__ mask,     // (S,B)
                                                  float* __restrict__ attn_ws,        // (B,T,S)
                                                  float* __restrict__ covloss_out) {  // (T*B,)
    int b = blockIdx.x, s = threadIdx.x;
    __shared__ float dp[64], wcov[64], wo[64], red[8];
    float ep[64];
    const float* ebase = encp + ((size_t)s * B_ + b) * A_;
#pragma unroll
    for (int a4 = 0; a4 < 16; ++a4) {
        float4 v = reinterpret_cast<const float4*>(ebase)[a4];
        ep[a4 * 4 + 0] = v.x; ep[a4 * 4 + 1] = v.y; ep[a4 * 4 + 2] = v.z; ep[a4 * 4 + 3] = v.w;
    }
    float msk = mask[s * B_ + b];
    float cov = 0.f;
    if (s < 64) { wcov[s] = Watt[s * 769 + 768]; wo[s] = Wout[s]; }
    __syncthreads();
    for (int t = 0; t < T_; ++t) {
        if (s < 64) dp[s] = decp[(t * B_ + b) * A_ + s];
        __syncthreads();
        float sc = 0.f;
#pragma unroll 8
        for (int a = 0; a < 64; ++a) sc += tanh_f(ep[a] + dp[a] + cov * wcov[a]) * wo[a];
        sc += msk;
        float mx = wred_max(sc);
        if ((s & 63) == 0) red[s >> 6] = mx;
        __syncthreads();
        mx = fmaxf(fmaxf(fmaxf(red[0], red[1]), fmaxf(red[2], red[3])),
                   fmaxf(fmaxf(red[4], red[5]), fmaxf(red[6], red[7])));
        float p = __expf(sc - mx);
        float su = wred_sum(p);
        __syncthreads();
        if ((s & 63) == 0) red[s >> 6] = su;
        __syncthreads();
        su = (red[0] + red[1]) + (red[2] + red[3]) + (red[4] + red[5]) + (red[6] + red[7]);
        float at = p / su;
        float cl = wred_sum(fminf(at, cov));
        __syncthreads();
        if ((s & 63) == 0) red[s >> 6] = cl;
        __syncthreads();
        if (s == 0)
            covloss_out[t * B_ + b] = (red[0] + red[1]) + (red[2] + red[3]) + (red[4] + red[5]) + (red[6] + red[7]);
        attn_ws[((size_t)b * T_ + t) * S_ + s] = at;
        cov += at;
        __syncthreads();
    }
}

// ---------------- attention context: ctx(T,128-tile) = attn(T,S) @ enc(S,b,dtile), enc read once ----------------
__global__ __launch_bounds__(256) void k_att_ctx(const float* __restrict__ enc,      // (S,B,512)
                                                 const float* __restrict__ attn_ws,  // (B,T,S)
                                                 float* __restrict__ pvin) {         // (T*B,768) cols 256..
    int b = blockIdx.x >> 2, dt = blockIdx.x & 3;
    int tid = threadIdx.x;
    __shared__ float ats[32 * 33];    // [t][s-chunk] padded
    __shared__ float es[32 * 132];    // [s][d] padded
    int ti = tid >> 5;               // 0..7 -> 4 t each
    int dj = tid & 31;               // 0..31 -> 4 d each
    float c[4][4] = {};
    for (int s0 = 0; s0 < S_; s0 += 32) {
        __syncthreads();
#pragma unroll
        for (int p = 0; p < 4; ++p) {
            int q = tid + p * 256;           // 0..1023 -> 32t x 32s
            int tt = q >> 5, ss = q & 31;
            ats[tt * 33 + ss] = attn_ws[((size_t)b * T_ + tt) * S_ + s0 + ss];
        }
#pragma unroll
        for (int p = 0; p < 4; ++p) {
            int q = tid + p * 256;           // 0..1023 -> 32s x 32 float4
            int ss = q >> 5, c4 = q & 31;
            float4 v = *reinterpret_cast<const float4*>(enc + (size_t)(s0 + ss) * (B_ * 512) + b * 512 + dt * 128 + c4 * 4);
            *reinterpret_cast<float4*>(&es[ss * 132 + c4 * 4]) = v;
        }
        __syncthreads();
#pragma unroll 4
        for (int s2 = 0; s2 < 32; ++s2) {
            float4 bv = *reinterpret_cast<const float4*>(&es[s2 * 132 + dj * 4]);
            float a0 = ats[(ti * 4 + 0) * 33 + s2];
            float a1 = ats[(ti * 4 + 1) * 33 + s2];
            float a2 = ats[(ti * 4 + 2) * 33 + s2];
            float a3 = ats[(ti * 4 + 3) * 33 + s2];
            c[0][0] += a0 * bv.x; c[0][1] += a0 * bv.y; c[0][2] += a0 * bv.z; c[0][3] += a0 * bv.w;
            c[1][0] += a1 * bv.x; c[1][1] += a1 * bv.y; c[1][2] += a1 * bv.z; c[1][3] += a1 * bv.w;
            c[2][0] += a2 * bv.x; c[2][1] += a2 * bv.y; c[2][2] += a2 * bv.z; c[2][3] += a2 * bv.w;
            c[3][0] += a3 * bv.x; c[3][1] += a3 * bv.y; c[3][2] += a3 * bv.z; c[3][3] += a3 * bv.w;
        }
    }
#pragma unroll
    for (int u = 0; u < 4; ++u) {
        int t = ti * 4 + u;
        float4 o = {c[u][0], c[u][1], c[u][2], c[u][3]};
        *reinterpret_cast<float4*>(pvin + (size_t)(t * B_ + b) * 768 + 256 + dt * 128 + dj * 4) = o;
    }
}

// ---------------- h1 f32 -> bf16 hi/lo ----------------
__global__ __launch_bounds__(256) void k_convert_h1(const float* __restrict__ h1,
                                                    unsigned short* __restrict__ hh,
                                                    unsigned short* __restrict__ hl) {
    int i = (blockIdx.x * 256 + threadIdx.x) * 4;
    float4 v = *reinterpret_cast<const float4*>(h1 + i);
    float f[4] = {v.x, v.y, v.z, v.w};
    unsigned short h[4], l[4];
#pragma unroll
    for (int j = 0; j < 4; ++j) {
        h[j] = bf16_rne(f[j]);
        float hf = __uint_as_float((unsigned)h[j] << 16);
        l[j] = bf16_rne(f[j] - hf);
    }
    *reinterpret_cast<ushort4*>(hh + i) = make_ushort4(h[0], h[1], h[2], h[3]);
    *reinterpret_cast<ushort4*>(hl + i) = make_ushort4(l[0], l[1], l[2], l[3]);
}

// ---------------- pvocab: split-bf16 MFMA GEMM, C(1024,50000) = h1 @ W_v2^T + b_v2 ----------------
// One block per 64-wide N tile; loops all M in 4 chunks of 256. W_v2 streamed once (f32->hi/lo on the fly).
__global__ __launch_bounds__(256, 2) void k_pvocab(const unsigned short* __restrict__ h1h,
                                                   const unsigned short* __restrict__ h1l,
                                                   const float* __restrict__ w2,
                                                   const float* __restrict__ bias,
                                                   float* __restrict__ C) {
    __shared__ bf16x8 Ah[4][256];
    __shared__ bf16x8 Al[4][256];
    __shared__ bf16x8 Bh[4][64];
    __shared__ bf16x8 Bl[4][64];
    int tid = threadIdx.x;
    int lane = tid & 63;
    int w = tid >> 6;
    int n0 = blockIdx.x * 64;
    int brow = tid >> 2, bc = tid & 3;
    int nB = n0 + brow;
    int l15 = lane & 15, lq = lane >> 4;

    for (int mc = 0; mc < 4; ++mc) {
        f32x4 acc[4][4];
#pragma unroll
        for (int i = 0; i < 4; ++i)
#pragma unroll
            for (int j = 0; j < 4; ++j) acc[i][j] = (f32x4){0.f, 0.f, 0.f, 0.f};

        for (int k0 = 0; k0 < 1024; k0 += 32) {
            // stage A (hi+lo bf16): 256 rows x 32k
#pragma unroll
            for (int p = 0; p < 4; ++p) {
                int q = tid + p * 256;
                int row = q >> 2, cc = q & 3;
                size_t off = (size_t)(mc * 256 + row) * 1024 + k0 + cc * 8;
                Ah[cc][row] = *reinterpret_cast<const bf16x8*>(h1h + off);
                Al[cc][row] = *reinterpret_cast<const bf16x8*>(h1l + off);
            }
            // stage B: load f32, split to hi/lo bf16
            {
                float f[8];
                if (nB < V_) {
                    const float* src = w2 + (size_t)nB * 1024 + k0 + bc * 8;
                    float4 f0 = *reinterpret_cast<const float4*>(src);
                    float4 f1 = *reinterpret_cast<const float4*>(src + 4);
                    f[0] = f0.x; f[1] = f0.y; f[2] = f0.z; f[3] = f0.w;
                    f[4] = f1.x; f[5] = f1.y; f[6] = f1.z; f[7] = f1.w;
                } else {
#pragma unroll
                    for (int j = 0; j < 8; ++j) f[j] = 0.f;
                }
                bf16x8 hv, lv;
#pragma unroll
                for (int j = 0; j < 8; ++j) {
                    unsigned short hb = bf16_rne(f[j]);
                    float hf = __uint_as_float((unsigned)hb << 16);
                    hv[j] = (short)hb;
                    lv[j] = (short)bf16_rne(f[j] - hf);
                }
                Bh[bc][brow] = hv;
                Bl[bc][brow] = lv;
            }
            __syncthreads();
            bf16x8 ah[4], al[4], bh[4], bl[4];
#pragma unroll
            for (int mt = 0; mt < 4; ++mt) {
                int r = w * 64 + mt * 16 + l15;
                ah[mt] = Ah[lq][r];
                al[mt] = Al[lq][r];
            }
#pragma unroll
            for (int nt = 0; nt < 4; ++nt) {
                int r = nt * 16 + l15;
                bh[nt] = Bh[lq][r];
                bl[nt] = Bl[lq][r];
            }
#pragma unroll
            for (int mt = 0; mt < 4; ++mt)
#pragma unroll
                for (int nt = 0; nt < 4; ++nt) {
                    acc[mt][nt] = __builtin_amdgcn_mfma_f32_16x16x32_bf16(ah[mt], bh[nt], acc[mt][nt], 0, 0, 0);
                    acc[mt][nt] = __builtin_amdgcn_mfma_f32_16x16x32_bf16(ah[mt], bl[nt], acc[mt][nt], 0, 0, 0);
                    acc[mt][nt] = __builtin_amdgcn_mfma_f32_16x16x32_bf16(al[mt], bh[nt], acc[mt][nt], 0, 0, 0);
                }
            __syncthreads();
        }
#pragma unroll
        for (int nt = 0; nt < 4; ++nt) {
            int n = n0 + nt * 16 + l15;
            if (n < V_) {
                float bv = bias[n];
#pragma unroll
                for (int mt = 0; mt < 4; ++mt)
#pragma unroll
                    for (int r = 0; r < 4; ++r) {
                        int m = mc * 256 + w * 64 + mt * 16 + lq * 4 + r;
                        C[(size_t)m * V_ + n] = acc[mt][nt][r] + bv;
                    }
            }
        }
    }
}

extern "C" void kernel_launch(void* const* d_in, const int* in_sizes, int n_in,
                              void* d_out, int out_size, void* d_ws, size_t ws_size,
                              hipStream_t stream) {
    const float* output_enc = (const float*)d_in[0];
    const float* input_dec  = (const float*)d_in[1];
    const float* hidden_enc = (const float*)d_in[2];
    const float* cell_enc   = (const float*)d_in[3];
    const float* att_mask   = (const float*)d_in[4];
    const float* W_ih0 = (const float*)d_in[5];
    const float* W_hh0 = (const float*)d_in[6];
    const float* b_ih0 = (const float*)d_in[7];
    const float* b_hh0 = (const float*)d_in[8];
    const float* W_ih1 = (const float*)d_in[9];
    const float* W_hh1 = (const float*)d_in[10];
    const float* b_ih1 = (const float*)d_in[11];
    const float* b_hh1 = (const float*)d_in[12];
    const float* W_red = (const float*)d_in[13];
    const float* b_red = (const float*)d_in[14];
    const float* W_att = (const float*)d_in[15];
    const float* b_att = (const float*)d_in[16];
    const float* W_attout = (const float*)d_in[17];
    const float* W_v1 = (const float*)d_in[18];
    const float* b_v1 = (const float*)d_in[19];
    const float* W_v2 = (const float*)d_in[20];
    const float* b_v2 = (const float*)d_in[21];
    float* out = (float*)d_out;
    float* ws  = (float*)d_ws;

    // workspace layout (floats)
    float* WT0     = ws;                    // 262144
    float* WT1     = WT0 + 262144;          // 262144
    float* newenc  = WT1 + 262144;          // 16384
    float* newcell = newenc + 16384;        // 16384
    float* gx0     = newcell + 16384;       // 1048576 (reused as h1h/h1l bf16 later)
    float* gx1     = gx0 + 1048576;         // 1048576
    float* y0      = gx1 + 1048576;         // 262144
    float* pvin    = y0 + 262144;           // 786432
    float* encp    = pvin + 786432;         // 1048576
    float* decp    = encp + 1048576;        // 65536
    float* h1      = decp + 65536;          // 1048576
    float* attn    = h1 + 1048576;          // 524288
    unsigned short* h1h = (unsigned short*)gx0;   // 1048576 bf16
    unsigned short* h1l = h1h + 1048576;          // 1048576 bf16

    float* out_pv = out;
    float* out_cl = out + 51200000;
    float* out_h  = out + 51201024;
    float* out_c  = out + 51217408;

    k_transpose_whh<<<2048, 256, 0, stream>>>(W_hh0, W_hh1, WT0, WT1);
    k_reduce<<<128, 256, 0, stream>>>(hidden_enc, cell_enc, W_red, b_red, newenc, newcell);
    // gates_x0 = input_dec @ W_ih0^T + (b_ih0+b_hh0): M=1024 N=1024 K=128
    k_gemm64<<<dim3(16, 16), 256, 0, stream>>>(input_dec, 128, W_ih0, 128, b_ih0, b_hh0, gx0, 1024, 128);
    // enc_proj = output_enc @ Wa_enc^T + b_att: M=16384 N=64 K=512 (ldb=769)
    k_gemm64<<<dim3(256, 1), 256, 0, stream>>>(output_enc, 512, W_att, 769, b_att, nullptr, encp, 64, 512);
    // LSTM layer 0 (consumes gx0)
    k_lstm<<<32, 1024, 0, stream>>>(gx0, WT0, newenc, newcell, y0, 256, out_h, out_c);
    // gates_x1 = y0 @ W_ih1^T + (b_ih1+b_hh1): M=1024 N=1024 K=256
    k_gemm64<<<dim3(16, 16), 256, 0, stream>>>(y0, 256, W_ih1, 256, b_ih1, b_hh1, gx1, 1024, 256);
    // LSTM layer 1 -> pv_in cols 0..255 (ld 768)
    k_lstm<<<32, 1024, 0, stream>>>(gx1, WT1, newenc + 8192, newcell + 8192, pvin, 768, out_h + 8192, out_c + 8192);
    // dec_proj = output_dec @ Wa_dec^T: M=1024 N=64 K=256
    k_gemm64<<<dim3(16, 1), 256, 0, stream>>>(pvin, 768, W_att + 512, 769, nullptr, nullptr, decp, 64, 256);
    // attention sequential scan -> attn (B,T,S), coverage_loss
    k_att_scan<<<32, 512, 0, stream>>>(encp, decp, W_att, W_attout, att_mask, attn, out_cl);
    // context = attn @ enc (enc read once) -> pv_in cols 256..767
    k_att_ctx<<<128, 256, 0, stream>>>(output_enc, attn, pvin);
    // h1 = pv_in @ W_v1^T + b_v1: M=1024 N=1024 K=768
    k_gemm64<<<dim3(16, 16), 256, 0, stream>>>(pvin, 768, W_v1, 768, b_v1, nullptr, h1, 1024, 768);
    // h1 -> bf16 hi/lo (into dead gx0)
    k_convert_h1<<<1024, 256, 0, stream>>>(h1, h1h, h1l);
    // pvocab = h1 @ W_v2^T + b_v2 via split-bf16 MFMA: M=1024 N=50000 K=1024
    k_pvocab<<<782, 256, 0, stream>>>(h1h, h1l, W_v2, b_v2, out_pv);
}

// Round 3
// 1567.725 us; speedup vs baseline: 1.3567x; 1.3567x over previous
//
#include <hip/hip_runtime.h>
#include <hip/hip_bf16.h>
#include <cstddef>

#define H_    256
#define INP_  128
#define A_    64
#define F_    1024
#define V_    50000
#define S_    512
#define T_    32
#define B_    32
#define G4_   1024   // 4*H

typedef __attribute__((ext_vector_type(8))) _Float16 f16x8;
typedef __attribute__((ext_vector_type(4))) _Float16 f16x4;
typedef __attribute__((ext_vector_type(4))) float f32x4;

__device__ __forceinline__ float sigm_f(float x) { return 1.f / (1.f + __expf(-x)); }
__device__ __forceinline__ float tanh_f(float x) { float e = __expf(2.f * x); return 1.f - 2.f / (e + 1.f); }

__device__ __forceinline__ float wred_max(float v) {
#pragma unroll
    for (int o = 1; o < 64; o <<= 1) v = fmaxf(v, __shfl_xor(v, o));
    return v;
}
__device__ __forceinline__ float wred_sum(float v) {
#pragma unroll
    for (int o = 1; o < 64; o <<= 1) v += __shfl_xor(v, o);
    return v;
}

// async 16B global -> LDS (linear dest, per-lane source)
__device__ __forceinline__ void glds16(const void* g, void* l) {
    __builtin_amdgcn_global_load_lds((const __attribute__((address_space(1))) unsigned int*)g,
                                     (__attribute__((address_space(3))) unsigned int*)l, 16, 0, 0);
}

// ---------------- transpose W_hh (1024x256) -> WT (256x1024), both layers ----------------
__global__ __launch_bounds__(256) void k_transpose_whh(const float* __restrict__ W0,
                                                       const float* __restrict__ W1,
                                                       float* __restrict__ T0,
                                                       float* __restrict__ T1) {
    int idx = blockIdx.x * 256 + threadIdx.x;
    int layer = idx >> 18;
    int i = idx & 262143;
    int k = i >> 10;
    int r = i & 1023;
    const float* W = layer ? W1 : W0;
    float* Tp = layer ? T1 : T0;
    Tp[i] = W[r * H_ + k];
}

// ---------------- reduce: new_enc/new_cell (2,B,H) ----------------
__global__ __launch_bounds__(256) void k_reduce(const float* __restrict__ hid,
                                                const float* __restrict__ cel,
                                                const float* __restrict__ Wred,
                                                const float* __restrict__ bred,
                                                float* __restrict__ ne,
                                                float* __restrict__ nc) {
    int idx = blockIdx.x * 256 + threadIdx.x;
    int arr = idx >> 14;
    int rem = idx & 16383;
    int l = rem >> 13;
    int b = (rem >> 8) & 31;
    int j = rem & 255;
    const float* src = arr ? cel : hid;
    const float* w = Wred + j * 512;
    const float* s0 = src + (l * B_ + b) * H_;
    const float* s1 = src + ((l + 2) * B_ + b) * H_;
    float acc = bred[j];
#pragma unroll 8
    for (int d = 0; d < 256; ++d) acc += s0[d] * w[d];
#pragma unroll 8
    for (int d = 0; d < 256; ++d) acc += s1[d] * w[256 + d];
    float* dst = arr ? nc : ne;
    dst[l * (B_ * H_) + b * H_ + j] = acc;
}

// ---------------- generic 64x64 f32 GEMM (NT): C[m,n] = sum_k A[m,k]*B[n,k] + bias ----------------
__global__ __launch_bounds__(256) void k_gemm64(const float* __restrict__ A, int lda,
                                                const float* __restrict__ Bm, int ldb,
                                                const float* __restrict__ bias1,
                                                const float* __restrict__ bias2,
                                                float* __restrict__ C, int ldc, int K) {
    __shared__ float As[32 * 65];
    __shared__ float Bs[32 * 65];
    int tid = threadIdx.x;
    int m0 = blockIdx.x * 64, n0 = blockIdx.y * 64;
    int mym = (tid >> 4) * 4, myn = (tid & 15) * 4;
    float c[4][4] = {};
    for (int k0 = 0; k0 < K; k0 += 32) {
        __syncthreads();
#pragma unroll
        for (int p = 0; p < 8; ++p) {
            int idx = tid + p * 256;
            int k = idx & 31, m = idx >> 5;
            As[k * 65 + m] = A[(size_t)(m0 + m) * lda + k0 + k];
            Bs[k * 65 + m] = Bm[(size_t)(n0 + m) * ldb + k0 + k];
        }
        __syncthreads();
#pragma unroll
        for (int k = 0; k < 32; ++k) {
            float a0 = As[k * 65 + mym + 0];
            float a1 = As[k * 65 + mym + 1];
            float a2 = As[k * 65 + mym + 2];
            float a3 = As[k * 65 + mym + 3];
            float b0 = Bs[k * 65 + myn + 0];
            float b1 = Bs[k * 65 + myn + 1];
            float b2 = Bs[k * 65 + myn + 2];
            float b3 = Bs[k * 65 + myn + 3];
            c[0][0] += a0 * b0; c[0][1] += a0 * b1; c[0][2] += a0 * b2; c[0][3] += a0 * b3;
            c[1][0] += a1 * b0; c[1][1] += a1 * b1; c[1][2] += a1 * b2; c[1][3] += a1 * b3;
            c[2][0] += a2 * b0; c[2][1] += a2 * b1; c[2][2] += a2 * b2; c[2][3] += a2 * b3;
            c[3][0] += a3 * b0; c[3][1] += a3 * b1; c[3][2] += a3 * b2; c[3][3] += a3 * b3;
        }
    }
    float bj[4];
#pragma unroll
    for (int j = 0; j < 4; ++j) {
        int n = n0 + myn + j;
        bj[j] = (bias1 ? bias1[n] : 0.f) + (bias2 ? bias2[n] : 0.f);
    }
#pragma unroll
    for (int i = 0; i < 4; ++i) {
        size_t off = (size_t)(m0 + mym + i) * ldc + n0 + myn;
#pragma unroll
        for (int j = 0; j < 4; ++j) C[off + j] = c[i][j] + bj[j];
    }
}

// ---------------- LSTM layer: one block per batch element, recurrence in LDS ----------------
__global__ __launch_bounds__(1024) void k_lstm(const float* __restrict__ gx,
                                               const float* __restrict__ WT,   // (256,1024) k-major
                                               const float* __restrict__ h0,
                                               const float* __restrict__ c0,
                                               float* __restrict__ y, int ldy,
                                               float* __restrict__ outh,
                                               float* __restrict__ outc) {
    int b = blockIdx.x, tid = threadIdx.x;
    __shared__ float h_s[256], c_s[256], g_s[1024];
    if (tid < 256) { h_s[tid] = h0[b * H_ + tid]; c_s[tid] = c0[b * H_ + tid]; }
    __syncthreads();
    for (int t = 0; t < T_; ++t) {
        float base = gx[(size_t)(t * B_ + b) * G4_ + tid];
        const float* wp = WT + tid;
        float a0 = 0.f, a1 = 0.f, a2 = 0.f, a3 = 0.f;
#pragma unroll 2
        for (int k = 0; k < 256; k += 4) {
            a0 += wp[(size_t)(k + 0) * G4_] * h_s[k + 0];
            a1 += wp[(size_t)(k + 1) * G4_] * h_s[k + 1];
            a2 += wp[(size_t)(k + 2) * G4_] * h_s[k + 2];
            a3 += wp[(size_t)(k + 3) * G4_] * h_s[k + 3];
        }
        g_s[tid] = base + (a0 + a1) + (a2 + a3);
        __syncthreads();
        if (tid < 256) {
            float ii = sigm_f(g_s[tid]);
            float ff = sigm_f(g_s[256 + tid]);
            float gg = tanh_f(g_s[512 + tid]);
            float oo = sigm_f(g_s[768 + tid]);
            float cc = ff * c_s[tid] + ii * gg;
            float hh = oo * tanh_f(cc);
            c_s[tid] = cc; h_s[tid] = hh;
            y[(size_t)(t * B_ + b) * ldy + tid] = hh;
        }
        __syncthreads();
    }
    if (tid < 256) { outh[b * H_ + tid] = h_s[tid]; outc[b * H_ + tid] = c_s[tid]; }
}

// ---------------- attention scan: sequential part only (no enc reads) ----------------
__global__ __launch_bounds__(512) void k_att_scan(const float* __restrict__ encp,     // (S*B,64)
                                                  const float* __restrict__ decp,     // (T*B,64)
                                                  const float* __restrict__ Watt,     // (64,769)
                                                  const float* __restrict__ Wout,     // (64,)
                                                  const float* __restrict__ mask,     // (S,B)
                                                  float* __restrict__ attn_ws,        // (B,T,S)
                                                  float* __restrict__ covloss_out) {  // (T*B,)
    int b = blockIdx.x, s = threadIdx.x;
    __shared__ float dp[64], wcov[64], wo[64], red[8];
    float ep[64];
    const float* ebase = encp + ((size_t)s * B_ + b) * A_;
#pragma unroll
    for (int a4 = 0; a4 < 16; ++a4) {
        float4 v = reinterpret_cast<const float4*>(ebase)[a4];
        ep[a4 * 4 + 0] = v.x; ep[a4 * 4 + 1] = v.y; ep[a4 * 4 + 2] = v.z; ep[a4 * 4 + 3] = v.w;
    }
    float msk = mask[s * B_ + b];
    float cov = 0.f;
    if (s < 64) { wcov[s] = Watt[s * 769 + 768]; wo[s] = Wout[s]; }
    __syncthreads();
    for (int t = 0; t < T_; ++t) {
        if (s < 64) dp[s] = decp[(t * B_ + b) * A_ + s];
        __syncthreads();
        float sc = 0.f;
#pragma unroll 8
        for (int a = 0; a < 64; ++a) sc += tanh_f(ep[a] + dp[a] + cov * wcov[a]) * wo[a];
        sc += msk;
        float mx = wred_max(sc);
        if ((s & 63) == 0) red[s >> 6] = mx;
        __syncthreads();
        mx = fmaxf(fmaxf(fmaxf(red[0], red[1]), fmaxf(red[2], red[3])),
                   fmaxf(fmaxf(red[4], red[5]), fmaxf(red[6], red[7])));
        float p = __expf(sc - mx);
        float su = wred_sum(p);
        __syncthreads();
        if ((s & 63) == 0) red[s >> 6] = su;
        __syncthreads();
        su = (red[0] + red[1]) + (red[2] + red[3]) + (red[4] + red[5]) + (red[6] + red[7]);
        float at = p / su;
        float cl = wred_sum(fminf(at, cov));
        __syncthreads();
        if ((s & 63) == 0) red[s >> 6] = cl;
        __syncthreads();
        if (s == 0)
            covloss_out[t * B_ + b] = (red[0] + red[1]) + (red[2] + red[3]) + (red[4] + red[5]) + (red[6] + red[7]);
        attn_ws[((size_t)b * T_ + t) * S_ + s] = at;
        cov += at;
        __syncthreads();
    }
}

// ---------------- attention context: ctx(T,128-tile) = attn(T,S) @ enc(S,b,dtile), enc read once ----------------
__global__ __launch_bounds__(256) void k_att_ctx(const float* __restrict__ enc,      // (S,B,512)
                                                 const float* __restrict__ attn_ws,  // (B,T,S)
                                                 float* __restrict__ pvin) {         // (T*B,768) cols 256..
    int b = blockIdx.x >> 2, dt = blockIdx.x & 3;
    int tid = threadIdx.x;
    __shared__ float ats[32 * 33];
    __shared__ float es[32 * 132];
    int ti = tid >> 5;
    int dj = tid & 31;
    float c[4][4] = {};
    for (int s0 = 0; s0 < S_; s0 += 32) {
        __syncthreads();
#pragma unroll
        for (int p = 0; p < 4; ++p) {
            int q = tid + p * 256;
            int tt = q >> 5, ss = q & 31;
            ats[tt * 33 + ss] = attn_ws[((size_t)b * T_ + tt) * S_ + s0 + ss];
        }
#pragma unroll
        for (int p = 0; p < 4; ++p) {
            int q = tid + p * 256;
            int ss = q >> 5, c4 = q & 31;
            float4 v = *reinterpret_cast<const float4*>(enc + (size_t)(s0 + ss) * (B_ * 512) + b * 512 + dt * 128 + c4 * 4);
            *reinterpret_cast<float4*>(&es[ss * 132 + c4 * 4]) = v;
        }
        __syncthreads();
#pragma unroll 4
        for (int s2 = 0; s2 < 32; ++s2) {
            float4 bv = *reinterpret_cast<const float4*>(&es[s2 * 132 + dj * 4]);
            float a0 = ats[(ti * 4 + 0) * 33 + s2];
            float a1 = ats[(ti * 4 + 1) * 33 + s2];
            float a2 = ats[(ti * 4 + 2) * 33 + s2];
            float a3 = ats[(ti * 4 + 3) * 33 + s2];
            c[0][0] += a0 * bv.x; c[0][1] += a0 * bv.y; c[0][2] += a0 * bv.z; c[0][3] += a0 * bv.w;
            c[1][0] += a1 * bv.x; c[1][1] += a1 * bv.y; c[1][2] += a1 * bv.z; c[1][3] += a1 * bv.w;
            c[2][0] += a2 * bv.x; c[2][1] += a2 * bv.y; c[2][2] += a2 * bv.z; c[2][3] += a2 * bv.w;
            c[3][0] += a3 * bv.x; c[3][1] += a3 * bv.y; c[3][2] += a3 * bv.z; c[3][3] += a3 * bv.w;
        }
    }
#pragma unroll
    for (int u = 0; u < 4; ++u) {
        int t = ti * 4 + u;
        float4 o = {c[u][0], c[u][1], c[u][2], c[u][3]};
        *reinterpret_cast<float4*>(pvin + (size_t)(t * B_ + b) * 768 + 256 + dt * 128 + dj * 4) = o;
    }
}

// ---------------- h1 f32 -> fp16 ----------------
__global__ __launch_bounds__(256) void k_convert_h1(const float* __restrict__ h1,
                                                    _Float16* __restrict__ hf) {
    int i = (blockIdx.x * 256 + threadIdx.x) * 4;
    float4 v = *reinterpret_cast<const float4*>(h1 + i);
    f16x4 o = {(_Float16)v.x, (_Float16)v.y, (_Float16)v.z, (_Float16)v.w};
    *reinterpret_cast<f16x4*>(hf + i) = o;
}

// ---------------- pvocab: fp16 MFMA GEMM, C(1024,50000) = h1 @ W_v2^T + b_v2 ----------------
// m97-style: 128x128 tile, BK=32, 4 waves, A via global_load_lds (pre-swizzled src),
// B reg-staged f32->fp16 on the fly, LDS double-buffered, 1 barrier/K-step,
// XOR bank swizzle (chunk ^= (row>>1)&3), XCD-aware block decode.
__global__ __launch_bounds__(256, 2) void k_pvocab2(const _Float16* __restrict__ h1f,
                                                    const float* __restrict__ w2,
                                                    const float* __restrict__ bias,
                                                    float* __restrict__ C) {
    __shared__ _Float16 As[2][128 * 32];
    __shared__ _Float16 Bs[2][128 * 32];
    int tid = threadIdx.x;
    int lane = tid & 63, w = tid >> 6;
    // XCD-aware decode: 8 m-tiles of one n-tile land dispatch-adjacent (same XCD)
    int d = blockIdx.x;            // 0..3135
    int xd = d & 7, c = d >> 3;    // c in [0,392)
    int mtile = c & 7;
    int ntile = ((c >> 3) << 3) + xd;   // [0,392)
    int m0 = mtile * 128, n0 = ntile * 128;
    int wm = w >> 1, wn = w & 1;
    int l15 = lane & 15, lq = lane >> 4;

    // ---- A staging (global_load_lds, 2 wave-instrs per wave) ----
    int L0 = (w * 2) * 64 + lane;
    int L1 = L0 + 64;
    int am0 = L0 >> 2, as0 = L0 & 3;
    int am1 = L1 >> 2, as1 = L1 & 3;
    int ac0 = as0 ^ ((am0 >> 1) & 3);
    int ac1 = as1 ^ ((am1 >> 1) & 3);
    const _Float16* ag0 = h1f + (size_t)(m0 + am0) * 1024 + ac0 * 8;
    const _Float16* ag1 = h1f + (size_t)(m0 + am1) * 1024 + ac1 * 8;
    int adst0 = (w * 2) * 512;     // fp16 elems (1024B per wave-instr)
    int adst1 = adst0 + 512;

    // ---- B staging (reg-staged, f32 -> fp16) ----
    int br = tid >> 1, bhf = tid & 1;
    bool bok = (n0 + br) < V_;
    const float* bg = w2 + (size_t)(n0 + br) * 1024 + bhf * 16;
    int bsw = (br >> 1) & 3;
    int bo0 = br * 32 + ((bhf * 2) ^ bsw) * 8;
    int bo1 = br * 32 + ((bhf * 2 + 1) ^ bsw) * 8;

    // ---- fragment read offsets (swizzled) ----
    int aoff[4], boff[4];
#pragma unroll
    for (int mt = 0; mt < 4; ++mt) {
        int row = wm * 64 + mt * 16 + l15;
        aoff[mt] = row * 32 + ((lq ^ ((row >> 1) & 3)) * 8);
    }
#pragma unroll
    for (int nt = 0; nt < 4; ++nt) {
        int row = wn * 64 + nt * 16 + l15;
        boff[nt] = row * 32 + ((lq ^ ((row >> 1) & 3)) * 8);
    }

    f32x4 acc[4][4];
#pragma unroll
    for (int i = 0; i < 4; ++i)
#pragma unroll
        for (int j = 0; j < 4; ++j) acc[i][j] = (f32x4){0.f, 0.f, 0.f, 0.f};

    float4 bv0, bv1, bv2, bv3;
    // prologue: stage k-tile 0 into buf 0
    glds16(ag0, &As[0][adst0]);
    glds16(ag1, &As[0][adst1]);
    if (bok) {
        bv0 = *reinterpret_cast<const float4*>(bg + 0);
        bv1 = *reinterpret_cast<const float4*>(bg + 4);
        bv2 = *reinterpret_cast<const float4*>(bg + 8);
        bv3 = *reinterpret_cast<const float4*>(bg + 12);
    } else {
        bv0 = bv1 = bv2 = bv3 = make_float4(0.f, 0.f, 0.f, 0.f);
    }
    {
        f16x8 c0 = {(_Float16)bv0.x, (_Float16)bv0.y, (_Float16)bv0.z, (_Float16)bv0.w,
                    (_Float16)bv1.x, (_Float16)bv1.y, (_Float16)bv1.z, (_Float16)bv1.w};
        f16x8 c1 = {(_Float16)bv2.x, (_Float16)bv2.y, (_Float16)bv2.z, (_Float16)bv2.w,
                    (_Float16)bv3.x, (_Float16)bv3.y, (_Float16)bv3.z, (_Float16)bv3.w};
        *reinterpret_cast<f16x8*>(&Bs[0][bo0]) = c0;
        *reinterpret_cast<f16x8*>(&Bs[0][bo1]) = c1;
    }
    __syncthreads();

    for (int kt = 0; kt < 32; ++kt) {
        int cur = kt & 1, nxt = cur ^ 1;
        if (kt < 31) {
            int k1 = (kt + 1) * 32;
            glds16(ag0 + k1, &As[nxt][adst0]);
            glds16(ag1 + k1, &As[nxt][adst1]);
            if (bok) {
                bv0 = *reinterpret_cast<const float4*>(bg + k1 + 0);
                bv1 = *reinterpret_cast<const float4*>(bg + k1 + 4);
                bv2 = *reinterpret_cast<const float4*>(bg + k1 + 8);
                bv3 = *reinterpret_cast<const float4*>(bg + k1 + 12);
            }
        }
        // compute on cur
        f16x8 af[4], bf[4];
#pragma unroll
        for (int mt = 0; mt < 4; ++mt) af[mt] = *reinterpret_cast<const f16x8*>(&As[cur][aoff[mt]]);
#pragma unroll
        for (int nt = 0; nt < 4; ++nt) bf[nt] = *reinterpret_cast<const f16x8*>(&Bs[cur][boff[nt]]);
#pragma unroll
        for (int mt = 0; mt < 4; ++mt)
#pragma unroll
            for (int nt = 0; nt < 4; ++nt)
                acc[mt][nt] = __builtin_amdgcn_mfma_f32_16x16x32_f16(af[mt], bf[nt], acc[mt][nt], 0, 0, 0);
        if (kt < 31) {
            f16x8 c0 = {(_Float16)bv0.x, (_Float16)bv0.y, (_Float16)bv0.z, (_Float16)bv0.w,
                        (_Float16)bv1.x, (_Float16)bv1.y, (_Float16)bv1.z, (_Float16)bv1.w};
            f16x8 c1 = {(_Float16)bv2.x, (_Float16)bv2.y, (_Float16)bv2.z, (_Float16)bv2.w,
                        (_Float16)bv3.x, (_Float16)bv3.y, (_Float16)bv3.z, (_Float16)bv3.w};
            *reinterpret_cast<f16x8*>(&Bs[nxt][bo0]) = c0;
            *reinterpret_cast<f16x8*>(&Bs[nxt][bo1]) = c1;
        }
        __syncthreads();
    }

    // epilogue
#pragma unroll
    for (int nt = 0; nt < 4; ++nt) {
        int n = n0 + wn * 64 + nt * 16 + l15;
        if (n < V_) {
            float bb = bias[n];
#pragma unroll
            for (int mt = 0; mt < 4; ++mt) {
                int mbase = m0 + wm * 64 + mt * 16 + lq * 4;
#pragma unroll
                for (int rr = 0; rr < 4; ++rr)
                    C[(size_t)(mbase + rr) * V_ + n] = acc[mt][nt][rr] + bb;
            }
        }
    }
}

extern "C" void kernel_launch(void* const* d_in, const int* in_sizes, int n_in,
                              void* d_out, int out_size, void* d_ws, size_t ws_size,
                              hipStream_t stream) {
    const float* output_enc = (const float*)d_in[0];
    const float* input_dec  = (const float*)d_in[1];
    const float* hidden_enc = (const float*)d_in[2];
    const float* cell_enc   = (const float*)d_in[3];
    const float* att_mask   = (const float*)d_in[4];
    const float* W_ih0 = (const float*)d_in[5];
    const float* W_hh0 = (const float*)d_in[6];
    const float* b_ih0 = (const float*)d_in[7];
    const float* b_hh0 = (const float*)d_in[8];
    const float* W_ih1 = (const float*)d_in[9];
    const float* W_hh1 = (const float*)d_in[10];
    const float* b_ih1 = (const float*)d_in[11];
    const float* b_hh1 = (const float*)d_in[12];
    const float* W_red = (const float*)d_in[13];
    const float* b_red = (const float*)d_in[14];
    const float* W_att = (const float*)d_in[15];
    const float* b_att = (const float*)d_in[16];
    const float* W_attout = (const float*)d_in[17];
    const float* W_v1 = (const float*)d_in[18];
    const float* b_v1 = (const float*)d_in[19];
    const float* W_v2 = (const float*)d_in[20];
    const float* b_v2 = (const float*)d_in[21];
    float* out = (float*)d_out;
    float* ws  = (float*)d_ws;

    // workspace layout (floats)
    float* WT0     = ws;                    // 262144
    float* WT1     = WT0 + 262144;          // 262144
    float* newenc  = WT1 + 262144;          // 16384
    float* newcell = newenc + 16384;        // 16384
    float* gx0     = newcell + 16384;       // 1048576 (reused as h1f fp16 later)
    float* gx1     = gx0 + 1048576;         // 1048576
    float* y0      = gx1 + 1048576;         // 262144
    float* pvin    = y0 + 262144;           // 786432
    float* encp    = pvin + 786432;         // 1048576
    float* decp    = encp + 1048576;        // 65536
    float* h1      = decp + 65536;          // 1048576
    float* attn    = h1 + 1048576;          // 524288
    _Float16* h1f  = (_Float16*)gx0;        // 1048576 fp16 (2 MB, inside dead gx0)

    float* out_pv = out;
    float* out_cl = out + 51200000;
    float* out_h  = out + 51201024;
    float* out_c  = out + 51217408;

    k_transpose_whh<<<2048, 256, 0, stream>>>(W_hh0, W_hh1, WT0, WT1);
    k_reduce<<<128, 256, 0, stream>>>(hidden_enc, cell_enc, W_red, b_red, newenc, newcell);
    // gates_x0 = input_dec @ W_ih0^T + (b_ih0+b_hh0): M=1024 N=1024 K=128
    k_gemm64<<<dim3(16, 16), 256, 0, stream>>>(input_dec, 128, W_ih0, 128, b_ih0, b_hh0, gx0, 1024, 128);
    // enc_proj = output_enc @ Wa_enc^T + b_att: M=16384 N=64 K=512 (ldb=769)
    k_gemm64<<<dim3(256, 1), 256, 0, stream>>>(output_enc, 512, W_att, 769, b_att, nullptr, encp, 64, 512);
    // LSTM layer 0 (consumes gx0)
    k_lstm<<<32, 1024, 0, stream>>>(gx0, WT0, newenc, newcell, y0, 256, out_h, out_c);
    // gates_x1 = y0 @ W_ih1^T + (b_ih1+b_hh1): M=1024 N=1024 K=256
    k_gemm64<<<dim3(16, 16), 256, 0, stream>>>(y0, 256, W_ih1, 256, b_ih1, b_hh1, gx1, 1024, 256);
    // LSTM layer 1 -> pv_in cols 0..255 (ld 768)
    k_lstm<<<32, 1024, 0, stream>>>(gx1, WT1, newenc + 8192, newcell + 8192, pvin, 768, out_h + 8192, out_c + 8192);
    // dec_proj = output_dec @ Wa_dec^T: M=1024 N=64 K=256
    k_gemm64<<<dim3(16, 1), 256, 0, stream>>>(pvin, 768, W_att + 512, 769, nullptr, nullptr, decp, 64, 256);
    // attention sequential scan -> attn (B,T,S), coverage_loss
    k_att_scan<<<32, 512, 0, stream>>>(encp, decp, W_att, W_attout, att_mask, attn, out_cl);
    // context = attn @ enc (enc read once) -> pv_in cols 256..767
    k_att_ctx<<<128, 256, 0, stream>>>(output_enc, attn, pvin);
    // h1 = pv_in @ W_v1^T + b_v1: M=1024 N=1024 K=768
    k_gemm64<<<dim3(16, 16), 256, 0, stream>>>(pvin, 768, W_v1, 768, b_v1, nullptr, h1, 1024, 768);
    // h1 -> fp16 (into dead gx0)
    k_convert_h1<<<1024, 256, 0, stream>>>(h1, h1f);
    // pvocab = h1 @ W_v2^T + b_v2 via fp16 MFMA: M=1024 N=50000(pad 50176) K=1024
    k_pvocab2<<<3136, 256, 0, stream>>>(h1f, W_v2, b_v2, out_pv);
}

// Round 4
// 1472.749 us; speedup vs baseline: 1.4442x; 1.0645x over previous
//
#include <hip/hip_runtime.h>
#include <hip/hip_bf16.h>
#include <cstddef>

#define H_    256
#define INP_  128
#define A_    64
#define F_    1024
#define V_    50000
#define S_    512
#define T_    32
#define B_    32
#define G4_   1024   // 4*H
#define NB_LSTM 64

typedef __attribute__((ext_vector_type(8))) _Float16 f16x8;
typedef __attribute__((ext_vector_type(4))) _Float16 f16x4;
typedef __attribute__((ext_vector_type(4))) float f32x4;

__device__ __forceinline__ float sigm_f(float x) { return 1.f / (1.f + __expf(-x)); }
__device__ __forceinline__ float tanh_f(float x) { float e = __expf(2.f * x); return 1.f - 2.f / (e + 1.f); }

__device__ __forceinline__ float wred_max(float v) {
#pragma unroll
    for (int o = 1; o < 64; o <<= 1) v = fmaxf(v, __shfl_xor(v, o));
    return v;
}
__device__ __forceinline__ float wred_sum(float v) {
#pragma unroll
    for (int o = 1; o < 64; o <<= 1) v += __shfl_xor(v, o);
    return v;
}

// async 16B global -> LDS (linear dest, per-lane source)
__device__ __forceinline__ void glds16(const void* g, void* l) {
    __builtin_amdgcn_global_load_lds((const __attribute__((address_space(1))) unsigned int*)g,
                                     (__attribute__((address_space(3))) unsigned int*)l, 16, 0, 0);
}

// device-scope grid sync (counter + generation). Blocks are 1/CU -> thread0's
// fences cover the whole block's L1. cnt/gen zeroed by k_pack every launch.
__device__ __forceinline__ void gsync(int* cnt, int* gen, int target, int nb) {
    __syncthreads();
    if (threadIdx.x == 0) {
        __threadfence();
        int v = __hip_atomic_fetch_add(cnt, 1, __ATOMIC_ACQ_REL, __HIP_MEMORY_SCOPE_AGENT);
        if (v == nb - 1) {
            __hip_atomic_store(cnt, 0, __ATOMIC_RELEASE, __HIP_MEMORY_SCOPE_AGENT);
            __hip_atomic_fetch_add(gen, 1, __ATOMIC_ACQ_REL, __HIP_MEMORY_SCOPE_AGENT);
        } else {
            while (__hip_atomic_load(gen, __ATOMIC_ACQUIRE, __HIP_MEMORY_SCOPE_AGENT) < target) {
                __builtin_amdgcn_s_sleep(2);
            }
        }
        __threadfence();
    }
    __syncthreads();
}

// ---------------- pack per-block LSTM weights (f32) + zero sync counters ----------------
// Wpk[seg][bk][r=cl*4+g][k], seg: 0=Whh0, 1=Whh1, 2=Wih1; src row = g*256 + bk*4 + cl
__global__ __launch_bounds__(256) void k_pack(const float* __restrict__ Whh0,
                                              const float* __restrict__ Whh1,
                                              const float* __restrict__ Wih1,
                                              float* __restrict__ Wpk,
                                              int* __restrict__ sync) {
    if (blockIdx.x == 0 && threadIdx.x < 2) sync[threadIdx.x] = 0;
    int idx = blockIdx.x * 256 + threadIdx.x;   // < 786432
    int k = idx & 255;
    int r = (idx >> 8) & 15;
    int bk = (idx >> 12) & 63;
    int seg = idx >> 18;
    int cl = r >> 2, g = r & 3;
    int srow = g * 256 + bk * 4 + cl;
    const float* W = seg == 0 ? Whh0 : (seg == 1 ? Whh1 : Wih1);
    Wpk[idx] = W[srow * 256 + k];
}

// ---------------- gather old_enc/old_cell rows into Ared (128 x 512) ----------------
__global__ __launch_bounds__(256) void k_gather(const float* __restrict__ hid,
                                                const float* __restrict__ cel,
                                                float* __restrict__ Ared) {
    int idx = blockIdx.x * 256 + threadIdx.x;  // < 65536
    int d = idx & 511;
    int r = idx >> 9;      // 0..127: arr*64 + l*32 + b
    int arr = r >> 6, l = (r >> 5) & 1, b = r & 31;
    const float* src = arr ? cel : hid;
    int lay = l + ((d >> 8) << 1);
    Ared[idx] = src[(lay * 32 + b) * 256 + (d & 255)];
}

// ---------------- generic 64x64 f32 GEMM (NT): C[m,n] = sum_k A[m,k]*B[n,k] + bias ----------------
__global__ __launch_bounds__(256) void k_gemm64(const float* __restrict__ A, int lda,
                                                const float* __restrict__ Bm, int ldb,
                                                const float* __restrict__ bias1,
                                                const float* __restrict__ bias2,
                                                float* __restrict__ C, int ldc, int K) {
    __shared__ float As[32 * 65];
    __shared__ float Bs[32 * 65];
    int tid = threadIdx.x;
    int m0 = blockIdx.x * 64, n0 = blockIdx.y * 64;
    int mym = (tid >> 4) * 4, myn = (tid & 15) * 4;
    float c[4][4] = {};
    for (int k0 = 0; k0 < K; k0 += 32) {
        __syncthreads();
#pragma unroll
        for (int p = 0; p < 8; ++p) {
            int idx = tid + p * 256;
            int k = idx & 31, m = idx >> 5;
            As[k * 65 + m] = A[(size_t)(m0 + m) * lda + k0 + k];
            Bs[k * 65 + m] = Bm[(size_t)(n0 + m) * ldb + k0 + k];
        }
        __syncthreads();
#pragma unroll
        for (int k = 0; k < 32; ++k) {
            float a0 = As[k * 65 + mym + 0];
            float a1 = As[k * 65 + mym + 1];
            float a2 = As[k * 65 + mym + 2];
            float a3 = As[k * 65 + mym + 3];
            float b0 = Bs[k * 65 + myn + 0];
            float b1 = Bs[k * 65 + myn + 1];
            float b2 = Bs[k * 65 + myn + 2];
            float b3 = Bs[k * 65 + myn + 3];
            c[0][0] += a0 * b0; c[0][1] += a0 * b1; c[0][2] += a0 * b2; c[0][3] += a0 * b3;
            c[1][0] += a1 * b0; c[1][1] += a1 * b1; c[1][2] += a1 * b2; c[1][3] += a1 * b3;
            c[2][0] += a2 * b0; c[2][1] += a2 * b1; c[2][2] += a2 * b2; c[2][3] += a2 * b3;
            c[3][0] += a3 * b0; c[3][1] += a3 * b1; c[3][2] += a3 * b2; c[3][3] += a3 * b3;
        }
    }
    float bj[4];
#pragma unroll
    for (int j = 0; j < 4; ++j) {
        int n = n0 + myn + j;
        bj[j] = (bias1 ? bias1[n] : 0.f) + (bias2 ? bias2[n] : 0.f);
    }
#pragma unroll
    for (int i = 0; i < 4; ++i) {
        size_t off = (size_t)(m0 + mym + i) * ldc + n0 + myn;
#pragma unroll
        for (int j = 0; j < 4; ++j) C[off + j] = c[i][j] + bj[j];
    }
}

// ---------------- same GEMM but fp16 output (for h1 -> pvocab A operand) ----------------
__global__ __launch_bounds__(256) void k_gemm64h(const float* __restrict__ A, int lda,
                                                 const float* __restrict__ Bm, int ldb,
                                                 const float* __restrict__ bias1,
                                                 _Float16* __restrict__ C16, int ldc, int K) {
    __shared__ float As[32 * 65];
    __shared__ float Bs[32 * 65];
    int tid = threadIdx.x;
    int m0 = blockIdx.x * 64, n0 = blockIdx.y * 64;
    int mym = (tid >> 4) * 4, myn = (tid & 15) * 4;
    float c[4][4] = {};
    for (int k0 = 0; k0 < K; k0 += 32) {
        __syncthreads();
#pragma unroll
        for (int p = 0; p < 8; ++p) {
            int idx = tid + p * 256;
            int k = idx & 31, m = idx >> 5;
            As[k * 65 + m] = A[(size_t)(m0 + m) * lda + k0 + k];
            Bs[k * 65 + m] = Bm[(size_t)(n0 + m) * ldb + k0 + k];
        }
        __syncthreads();
#pragma unroll
        for (int k = 0; k < 32; ++k) {
            float a0 = As[k * 65 + mym + 0];
            float a1 = As[k * 65 + mym + 1];
            float a2 = As[k * 65 + mym + 2];
            float a3 = As[k * 65 + mym + 3];
            float b0 = Bs[k * 65 + myn + 0];
            float b1 = Bs[k * 65 + myn + 1];
            float b2 = Bs[k * 65 + myn + 2];
            float b3 = Bs[k * 65 + myn + 3];
            c[0][0] += a0 * b0; c[0][1] += a0 * b1; c[0][2] += a0 * b2; c[0][3] += a0 * b3;
            c[1][0] += a1 * b0; c[1][1] += a1 * b1; c[1][2] += a1 * b2; c[1][3] += a1 * b3;
            c[2][0] += a2 * b0; c[2][1] += a2 * b1; c[2][2] += a2 * b2; c[2][3] += a2 * b3;
            c[3][0] += a3 * b0; c[3][1] += a3 * b1; c[3][2] += a3 * b2; c[3][3] += a3 * b3;
        }
    }
    float bj[4];
#pragma unroll
    for (int j = 0; j < 4; ++j) bj[j] = bias1[n0 + myn + j];
#pragma unroll
    for (int i = 0; i < 4; ++i) {
        size_t off = (size_t)(m0 + mym + i) * ldc + n0 + myn;
        f16x4 o = {(_Float16)(c[i][0] + bj[0]), (_Float16)(c[i][1] + bj[1]),
                   (_Float16)(c[i][2] + bj[2]), (_Float16)(c[i][3] + bj[3])};
        *reinterpret_cast<f16x4*>(C16 + off) = o;
    }
}

// ---------------- fused 2-layer LSTM, LDS-resident weights, grid-synced ----------------
// 64 blocks x 512 threads. Block bk owns cells [bk*4, bk*4+4). Thread: b=tid>>4,
// cl=(tid>>2)&3, g=tid&3. Layer1 step s-1 runs with layer0 step s (one sync/iter).
__global__ __launch_bounds__(512) void k_lstm2(const float* __restrict__ gx0,
                                               const float* __restrict__ Wpk,
                                               const float* __restrict__ newenc,
                                               const float* __restrict__ newcell,
                                               const float* __restrict__ bih1,
                                               const float* __restrict__ bhh1,
                                               float* __restrict__ h0g,   // [2][8192]
                                               float* __restrict__ h1g,   // [2][8192]
                                               float* __restrict__ pvin,  // (T*B,768) cols 0..255
                                               float* __restrict__ outh,
                                               float* __restrict__ outc,
                                               int* __restrict__ scnt,
                                               int* __restrict__ sgen) {
    __shared__ float W0s[16][260], W1h[16][260], W1i[16][260];
    __shared__ float bufA[32][260], bufB[32][260];
    int tid = threadIdx.x, bk = blockIdx.x;
    int b = tid >> 4, cl = (tid >> 2) & 3, g = tid & 3;
    int r = cl * 4 + g;
    int cellg = bk * 4 + cl;
    int row_w = g * 256 + cellg;
    // weights -> LDS (once)
    for (int i = tid; i < 16 * 256; i += 512) {
        int rr = i >> 8, kk = i & 255;
        W0s[rr][kk] = Wpk[((0 * 64 + bk) * 16 + rr) * 256 + kk];
        W1h[rr][kk] = Wpk[((1 * 64 + bk) * 16 + rr) * 256 + kk];
        W1i[rr][kk] = Wpk[((2 * 64 + bk) * 16 + rr) * 256 + kk];
    }
    float bs1 = bih1[row_w] + bhh1[row_w];
    float c0 = newcell[b * 256 + cellg];
    float c1 = newcell[8192 + b * 256 + cellg];
    // init h(-1) into buffer 1 (redundant identical writes across blocks: benign)
    for (int i = tid; i < 8192; i += 512) {
        h0g[8192 + i] = newenc[i];
        h1g[8192 + i] = newenc[8192 + i];
    }
    gsync(scnt, sgen, 1, NB_LSTM);
    int lq4 = (tid & 63) & ~3;
    int sb = tid >> 4, sk = (tid & 15) * 16;
    for (int s = 0; s <= 32; ++s) {
        // stage h0(s-1) -> bufA, h1(s-2) -> bufB
        const float* srcA = h0g + (((s + 1) & 1) << 13);
        const float* srcB = h1g + ((s & 1) << 13);
#pragma unroll
        for (int u = 0; u < 16; u += 4) {
            *reinterpret_cast<float4*>(&bufA[sb][sk + u]) =
                *reinterpret_cast<const float4*>(srcA + sb * 256 + sk + u);
            *reinterpret_cast<float4*>(&bufB[sb][sk + u]) =
                *reinterpret_cast<const float4*>(srcB + sb * 256 + sk + u);
        }
        __syncthreads();
        if (s < 32) {   // layer0 step s
            float acc = gx0[(size_t)(s * 32 + b) * 1024 + row_w];
            float a0 = 0.f, a1 = 0.f, a2 = 0.f, a3 = 0.f;
#pragma unroll 8
            for (int k = 0; k < 256; k += 4) {
                float4 wv = *reinterpret_cast<const float4*>(&W0s[r][k]);
                float4 hv = *reinterpret_cast<const float4*>(&bufA[b][k]);
                a0 = fmaf(wv.x, hv.x, a0); a1 = fmaf(wv.y, hv.y, a1);
                a2 = fmaf(wv.z, hv.z, a2); a3 = fmaf(wv.w, hv.w, a3);
            }
            acc += (a0 + a1) + (a2 + a3);
            float ii = __shfl(acc, lq4 + 0);
            float ff = __shfl(acc, lq4 + 1);
            float gg = __shfl(acc, lq4 + 2);
            float oo = __shfl(acc, lq4 + 3);
            c0 = sigm_f(ff) * c0 + sigm_f(ii) * tanh_f(gg);
            float h = sigm_f(oo) * tanh_f(c0);
            if (g == 0) {
                h0g[((s & 1) << 13) + b * 256 + cellg] = h;
                if (s == 31) outh[b * 256 + cellg] = h;
            }
            if (g == 1 && s == 31) outc[b * 256 + cellg] = c0;
        }
        if (s >= 1) {   // layer1 step s-1 (input = y0(s-1) = bufA)
            float acc = bs1;
            float a0 = 0.f, a1 = 0.f, a2 = 0.f, a3 = 0.f;
#pragma unroll 4
            for (int k = 0; k < 256; k += 4) {
                float4 wi = *reinterpret_cast<const float4*>(&W1i[r][k]);
                float4 ya = *reinterpret_cast<const float4*>(&bufA[b][k]);
                float4 wh = *reinterpret_cast<const float4*>(&W1h[r][k]);
                float4 hb = *reinterpret_cast<const float4*>(&bufB[b][k]);
                a0 = fmaf(wi.x, ya.x, a0); a1 = fmaf(wi.y, ya.y, a1);
                a2 = fmaf(wi.z, ya.z, a2); a3 = fmaf(wi.w, ya.w, a3);
                a0 = fmaf(wh.x, hb.x, a0); a1 = fmaf(wh.y, hb.y, a1);
                a2 = fmaf(wh.z, hb.z, a2); a3 = fmaf(wh.w, hb.w, a3);
            }
            acc += (a0 + a1) + (a2 + a3);
            float ii = __shfl(acc, lq4 + 0);
            float ff = __shfl(acc, lq4 + 1);
            float gg = __shfl(acc, lq4 + 2);
            float oo = __shfl(acc, lq4 + 3);
            c1 = sigm_f(ff) * c1 + sigm_f(ii) * tanh_f(gg);
            float h = sigm_f(oo) * tanh_f(c1);
            int t1 = s - 1;
            if (g == 0) {
                h1g[((t1 & 1) << 13) + b * 256 + cellg] = h;
                pvin[(size_t)(t1 * 32 + b) * 768 + cellg] = h;
                if (t1 == 31) outh[8192 + b * 256 + cellg] = h;
            }
            if (g == 1 && t1 == 31) outc[8192 + b * 256 + cellg] = c1;
        }
        gsync(scnt, sgen, s + 2, NB_LSTM);
    }
}

// ---------------- attention scan: sequential part only (no enc reads) ----------------
__global__ __launch_bounds__(512) void k_att_scan(const float* __restrict__ encp,
                                                  const float* __restrict__ decp,
                                                  const float* __restrict__ Watt,
                                                  const float* __restrict__ Wout,
                                                  const float* __restrict__ mask,
                                                  float* __restrict__ attn_ws,
                                                  float* __restrict__ covloss_out) {
    int b = blockIdx.x, s = threadIdx.x;
    __shared__ float dp[64], wcov[64], wo[64], red[8];
    float ep[64];
    const float* ebase = encp + ((size_t)s * B_ + b) * A_;
#pragma unroll
    for (int a4 = 0; a4 < 16; ++a4) {
        float4 v = reinterpret_cast<const float4*>(ebase)[a4];
        ep[a4 * 4 + 0] = v.x; ep[a4 * 4 + 1] = v.y; ep[a4 * 4 + 2] = v.z; ep[a4 * 4 + 3] = v.w;
    }
    float msk = mask[s * B_ + b];
    float cov = 0.f;
    if (s < 64) { wcov[s] = Watt[s * 769 + 768]; wo[s] = Wout[s]; }
    __syncthreads();
    for (int t = 0; t < T_; ++t) {
        if (s < 64) dp[s] = decp[(t * B_ + b) * A_ + s];
        __syncthreads();
        float sc = 0.f;
#pragma unroll 8
        for (int a = 0; a < 64; ++a) sc += tanh_f(ep[a] + dp[a] + cov * wcov[a]) * wo[a];
        sc += msk;
        float mx = wred_max(sc);
        if ((s & 63) == 0) red[s >> 6] = mx;
        __syncthreads();
        mx = fmaxf(fmaxf(fmaxf(red[0], red[1]), fmaxf(red[2], red[3])),
                   fmaxf(fmaxf(red[4], red[5]), fmaxf(red[6], red[7])));
        float p = __expf(sc - mx);
        float su = wred_sum(p);
        __syncthreads();
        if ((s & 63) == 0) red[s >> 6] = su;
        __syncthreads();
        su = (red[0] + red[1]) + (red[2] + red[3]) + (red[4] + red[5]) + (red[6] + red[7]);
        float at = p / su;
        float cl = wred_sum(fminf(at, cov));
        __syncthreads();
        if ((s & 63) == 0) red[s >> 6] = cl;
        __syncthreads();
        if (s == 0)
            covloss_out[t * B_ + b] = (red[0] + red[1]) + (red[2] + red[3]) + (red[4] + red[5]) + (red[6] + red[7]);
        attn_ws[((size_t)b * T_ + t) * S_ + s] = at;
        cov += at;
        __syncthreads();
    }
}

// ---------------- attention context: ctx = attn @ enc, enc read once ----------------
__global__ __launch_bounds__(256) void k_att_ctx(const float* __restrict__ enc,
                                                 const float* __restrict__ attn_ws,
                                                 float* __restrict__ pvin) {
    int b = blockIdx.x >> 2, dt = blockIdx.x & 3;
    int tid = threadIdx.x;
    __shared__ float ats[32 * 33];
    __shared__ float es[32 * 132];
    int ti = tid >> 5;
    int dj = tid & 31;
    float c[4][4] = {};
    for (int s0 = 0; s0 < S_; s0 += 32) {
        __syncthreads();
#pragma unroll
        for (int p = 0; p < 4; ++p) {
            int q = tid + p * 256;
            int tt = q >> 5, ss = q & 31;
            ats[tt * 33 + ss] = attn_ws[((size_t)b * T_ + tt) * S_ + s0 + ss];
        }
#pragma unroll
        for (int p = 0; p < 4; ++p) {
            int q = tid + p * 256;
            int ss = q >> 5, c4 = q & 31;
            float4 v = *reinterpret_cast<const float4*>(enc + (size_t)(s0 + ss) * (B_ * 512) + b * 512 + dt * 128 + c4 * 4);
            *reinterpret_cast<float4*>(&es[ss * 132 + c4 * 4]) = v;
        }
        __syncthreads();
#pragma unroll 4
        for (int s2 = 0; s2 < 32; ++s2) {
            float4 bv = *reinterpret_cast<const float4*>(&es[s2 * 132 + dj * 4]);
            float a0 = ats[(ti * 4 + 0) * 33 + s2];
            float a1 = ats[(ti * 4 + 1) * 33 + s2];
            float a2 = ats[(ti * 4 + 2) * 33 + s2];
            float a3 = ats[(ti * 4 + 3) * 33 + s2];
            c[0][0] += a0 * bv.x; c[0][1] += a0 * bv.y; c[0][2] += a0 * bv.z; c[0][3] += a0 * bv.w;
            c[1][0] += a1 * bv.x; c[1][1] += a1 * bv.y; c[1][2] += a1 * bv.z; c[1][3] += a1 * bv.w;
            c[2][0] += a2 * bv.x; c[2][1] += a2 * bv.y; c[2][2] += a2 * bv.z; c[2][3] += a2 * bv.w;
            c[3][0] += a3 * bv.x; c[3][1] += a3 * bv.y; c[3][2] += a3 * bv.z; c[3][3] += a3 * bv.w;
        }
    }
#pragma unroll
    for (int u = 0; u < 4; ++u) {
        int t = ti * 4 + u;
        float4 o = {c[u][0], c[u][1], c[u][2], c[u][3]};
        *reinterpret_cast<float4*>(pvin + (size_t)(t * B_ + b) * 768 + 256 + dt * 128 + dj * 4) = o;
    }
}

// ---------------- pvocab: fp16 MFMA GEMM, 256x128 tile, 8 waves, dbuf ----------------
__global__ __launch_bounds__(512, 4) void k_pvocab3(const _Float16* __restrict__ h1f,
                                                    const float* __restrict__ w2,
                                                    const float* __restrict__ bias,
                                                    float* __restrict__ C) {
    __shared__ _Float16 As[2][256 * 32];
    __shared__ _Float16 Bs[2][128 * 32];
    int tid = threadIdx.x;
    int lane = tid & 63, w = tid >> 6;
    int d = blockIdx.x;              // 0..1567
    int xd = d & 7, c = d >> 3;
    int mtile = c & 3;
    int ntile = (c >> 2) * 8 + xd;   // 0..391
    int m0 = mtile * 256, n0 = ntile * 128;
    int wm = w >> 1, wn = w & 1;
    int l15 = lane & 15, lq = lane >> 4;

    // A staging: slots q = w*128 + lane (+64); row = q>>2, chunk16B = q&3, pre-swizzled src
    int q0 = w * 128 + lane, q1 = q0 + 64;
    int ar0 = q0 >> 2, ac0 = (q0 & 3) ^ ((ar0 >> 1) & 3);
    int ar1 = q1 >> 2, ac1 = (q1 & 3) ^ ((ar1 >> 1) & 3);
    const _Float16* ag0 = h1f + (size_t)(m0 + ar0) * 1024 + ac0 * 8;
    const _Float16* ag1 = h1f + (size_t)(m0 + ar1) * 1024 + ac1 * 8;
    int adst0 = q0 * 8, adst1 = q1 * 8;

    // B staging: thread -> row = tid>>2, chunk = tid&3 (8 f32 each), swizzled LDS write
    int br = tid >> 2, bch = tid & 3;
    int bo = br * 32 + ((bch ^ ((br >> 1) & 3)) * 8);
    bool bok = (n0 + br) < V_;
    const float* bg = w2 + (size_t)(n0 + br) * 1024 + bch * 8;

    int aoff[4], boff[4];
#pragma unroll
    for (int mt = 0; mt < 4; ++mt) {
        int row = wm * 64 + mt * 16 + l15;
        aoff[mt] = row * 32 + ((lq ^ ((row >> 1) & 3)) * 8);
    }
#pragma unroll
    for (int nt = 0; nt < 4; ++nt) {
        int row = wn * 64 + nt * 16 + l15;
        boff[nt] = row * 32 + ((lq ^ ((row >> 1) & 3)) * 8);
    }

    f32x4 acc[4][4];
#pragma unroll
    for (int i = 0; i < 4; ++i)
#pragma unroll
        for (int j = 0; j < 4; ++j) acc[i][j] = (f32x4){0.f, 0.f, 0.f, 0.f};

    float4 bv0, bv1;
    glds16(ag0, &As[0][adst0]);
    glds16(ag1, &As[0][adst1]);
    if (bok) {
        bv0 = *reinterpret_cast<const float4*>(bg + 0);
        bv1 = *reinterpret_cast<const float4*>(bg + 4);
    } else {
        bv0 = bv1 = make_float4(0.f, 0.f, 0.f, 0.f);
    }
    {
        f16x8 c0 = {(_Float16)bv0.x, (_Float16)bv0.y, (_Float16)bv0.z, (_Float16)bv0.w,
                    (_Float16)bv1.x, (_Float16)bv1.y, (_Float16)bv1.z, (_Float16)bv1.w};
        *reinterpret_cast<f16x8*>(&Bs[0][bo]) = c0;
    }
    __syncthreads();

    for (int kt = 0; kt < 32; ++kt) {
        int cur = kt & 1, nxt = cur ^ 1;
        if (kt < 31) {
            int k1 = (kt + 1) * 32;
            glds16(ag0 + k1, &As[nxt][adst0]);
            glds16(ag1 + k1, &As[nxt][adst1]);
            if (bok) {
                bv0 = *reinterpret_cast<const float4*>(bg + k1 + 0);
                bv1 = *reinterpret_cast<const float4*>(bg + k1 + 4);
            }
        }
        f16x8 af[4], bf[4];
#pragma unroll
        for (int mt = 0; mt < 4; ++mt) af[mt] = *reinterpret_cast<const f16x8*>(&As[cur][aoff[mt]]);
#pragma unroll
        for (int nt = 0; nt < 4; ++nt) bf[nt] = *reinterpret_cast<const f16x8*>(&Bs[cur][boff[nt]]);
#pragma unroll
        for (int mt = 0; mt < 4; ++mt)
#pragma unroll
            for (int nt = 0; nt < 4; ++nt)
                acc[mt][nt] = __builtin_amdgcn_mfma_f32_16x16x32_f16(af[mt], bf[nt], acc[mt][nt], 0, 0, 0);
        if (kt < 31) {
            f16x8 c0 = {(_Float16)bv0.x, (_Float16)bv0.y, (_Float16)bv0.z, (_Float16)bv0.w,
                        (_Float16)bv1.x, (_Float16)bv1.y, (_Float16)bv1.z, (_Float16)bv1.w};
            *reinterpret_cast<f16x8*>(&Bs[nxt][bo]) = c0;
        }
        __syncthreads();
    }

#pragma unroll
    for (int nt = 0; nt < 4; ++nt) {
        int n = n0 + wn * 64 + nt * 16 + l15;
        if (n < V_) {
            float bb = bias[n];
#pragma unroll
            for (int mt = 0; mt < 4; ++mt) {
                int mbase = m0 + wm * 64 + mt * 16 + lq * 4;
#pragma unroll
                for (int rr = 0; rr < 4; ++rr)
                    C[(size_t)(mbase + rr) * V_ + n] = acc[mt][nt][rr] + bb;
            }
        }
    }
}

extern "C" void kernel_launch(void* const* d_in, const int* in_sizes, int n_in,
                              void* d_out, int out_size, void* d_ws, size_t ws_size,
                              hipStream_t stream) {
    const float* output_enc = (const float*)d_in[0];
    const float* input_dec  = (const float*)d_in[1];
    const float* hidden_enc = (const float*)d_in[2];
    const float* cell_enc   = (const float*)d_in[3];
    const float* att_mask   = (const float*)d_in[4];
    const float* W_ih0 = (const float*)d_in[5];
    const float* W_hh0 = (const float*)d_in[6];
    const float* b_ih0 = (const float*)d_in[7];
    const float* b_hh0 = (const float*)d_in[8];
    const float* W_ih1 = (const float*)d_in[9];
    const float* W_hh1 = (const float*)d_in[10];
    const float* b_ih1 = (const float*)d_in[11];
    const float* b_hh1 = (const float*)d_in[12];
    const float* W_red = (const float*)d_in[13];
    const float* b_red = (const float*)d_in[14];
    const float* W_att = (const float*)d_in[15];
    const float* b_att = (const float*)d_in[16];
    const float* W_attout = (const float*)d_in[17];
    const float* W_v1 = (const float*)d_in[18];
    const float* b_v1 = (const float*)d_in[19];
    const float* W_v2 = (const float*)d_in[20];
    const float* b_v2 = (const float*)d_in[21];
    float* out = (float*)d_out;
    float* ws  = (float*)d_ws;

    // workspace layout (floats)
    float* Wpk     = ws;                    // 786432
    float* Ared    = Wpk + 786432;          // 65536
    float* newenc  = Ared + 65536;          // 16384
    float* newcell = newenc + 16384;        // 16384 (must be adjacent to newenc)
    float* gx0     = newcell + 16384;       // 1048576
    float* h0g     = gx0 + 1048576;         // 16384 (2 x 8192)
    float* h1g     = h0g + 16384;           // 16384
    float* pvin    = h1g + 16384;           // 786432
    float* encp    = pvin + 786432;         // 1048576
    float* decp    = encp + 1048576;        // 65536
    float* attn    = decp + 65536;          // 524288
    _Float16* h1f  = (_Float16*)(attn + 524288);  // 1048576 halves (524288 floats)
    int* sync      = (int*)(attn + 524288 + 524288);

    float* out_pv = out;
    float* out_cl = out + 51200000;
    float* out_h  = out + 51201024;
    float* out_c  = out + 51217408;

    k_pack<<<3072, 256, 0, stream>>>(W_hh0, W_hh1, W_ih1, Wpk, sync);
    k_gather<<<256, 256, 0, stream>>>(hidden_enc, cell_enc, Ared);
    // new_enc/new_cell: (128 x 256) = Ared (128x512) @ W_red^T + b_red
    k_gemm64<<<dim3(2, 4), 256, 0, stream>>>(Ared, 512, W_red, 512, b_red, nullptr, newenc, 256, 512);
    // gates_x0 = input_dec @ W_ih0^T + (b_ih0+b_hh0)
    k_gemm64<<<dim3(16, 16), 256, 0, stream>>>(input_dec, 128, W_ih0, 128, b_ih0, b_hh0, gx0, 1024, 128);
    // enc_proj = output_enc @ Wa_enc^T + b_att
    k_gemm64<<<dim3(256, 1), 256, 0, stream>>>(output_enc, 512, W_att, 769, b_att, nullptr, encp, 64, 512);
    // fused 2-layer LSTM -> pvin cols 0..255, out_h, out_c
    k_lstm2<<<NB_LSTM, 512, 0, stream>>>(gx0, Wpk, newenc, newcell, b_ih1, b_hh1,
                                         h0g, h1g, pvin, out_h, out_c, sync, sync + 1);
    // dec_proj = output_dec @ Wa_dec^T
    k_gemm64<<<dim3(16, 1), 256, 0, stream>>>(pvin, 768, W_att + 512, 769, nullptr, nullptr, decp, 64, 256);
    // attention sequential scan -> attn (B,T,S), coverage_loss
    k_att_scan<<<32, 512, 0, stream>>>(encp, decp, W_att, W_attout, att_mask, attn, out_cl);
    // context = attn @ enc -> pvin cols 256..767
    k_att_ctx<<<128, 256, 0, stream>>>(output_enc, attn, pvin);
    // h1 = pvin @ W_v1^T + b_v1, stored fp16
    k_gemm64h<<<dim3(16, 16), 256, 0, stream>>>(pvin, 768, W_v1, 768, b_v1, h1f, 1024, 768);
    // pvocab = h1 @ W_v2^T + b_v2 (fp16 MFMA)
    k_pvocab3<<<1568, 512, 0, stream>>>(h1f, W_v2, b_v2, out_pv);
}